// Round 2
// baseline (57.198 us; speedup 1.0000x reference)
//
#include <hip/hip_runtime.h>

// Problem constants (from reference setup_inputs): B=8, N=2048, M=2048, D=128
#define B_DIM 8
#define N_DIM 2048
#define M_DIM 2048
#define D_DIM 128
#define BM 128
#define BN 128

typedef __bf16 bf16_t;
typedef bf16_t bf16x4 __attribute__((ext_vector_type(4)));
typedef bf16_t bf16x8 __attribute__((ext_vector_type(8)));
typedef float f32x4 __attribute__((ext_vector_type(4)));

#define GLOAD_LDS16(g, l)                                              \
    __builtin_amdgcn_global_load_lds(                                  \
        (const __attribute__((address_space(1))) void*)(g),            \
        (__attribute__((address_space(3))) void*)(l), 16, 0, 0)

// ---------------------------------------------------------------------------
// Kernel 1: fp32 -> bf16 (RNE) conversion + row norms from the SAME rounded
// values. One wave handles 2 rows (64 lanes = 2 x 32 float4 slots).
// ---------------------------------------------------------------------------
__global__ __launch_bounds__(256) void prep_kernel(
    const float* __restrict__ L, const float* __restrict__ R,
    bf16_t* __restrict__ Lb, bf16_t* __restrict__ Rb,
    float* __restrict__ nL, float* __restrict__ nR)
{
    const int tid  = threadIdx.x;
    const int wid  = tid >> 6;
    const int lane = tid & 63;
    const int row  = blockIdx.x * 8 + wid * 2 + (lane >> 5);  // [0, 16384)
    const int c4   = lane & 31;                                // float4 slot in row

    const float* src  = blockIdx.y ? R : L;
    bf16_t*      dst  = blockIdx.y ? Rb : Lb;
    float*       ndst = blockIdx.y ? nR : nL;

    float4 v = ((const float4*)src)[(size_t)row * 32 + c4];
    bf16x4 p = { (bf16_t)v.x, (bf16_t)v.y, (bf16_t)v.z, (bf16_t)v.w };
    ((bf16x4*)dst)[(size_t)row * 32 + c4] = p;

    float x0 = (float)p[0], x1 = (float)p[1], x2 = (float)p[2], x3 = (float)p[3];
    float s = fmaf(x0, x0, fmaf(x1, x1, fmaf(x2, x2, x3 * x3)));
    #pragma unroll
    for (int off = 1; off < 32; off <<= 1) s += __shfl_xor(s, off);
    if (c4 == 0) ndst[row] = s;
}

// ---------------------------------------------------------------------------
// Kernel 2: bf16 MFMA distance tile. LDS staged via global_load_lds width=16
// with pre-swizzled SOURCE addresses (LDS dest stays linear); reads apply the
// same XOR swizzle:  granule c' = c ^ (row & 7)  (16B granules, 16 per row).
// ---------------------------------------------------------------------------
__global__ __launch_bounds__(256) void dist_mfma_kernel(
    const bf16_t* __restrict__ Lb, const bf16_t* __restrict__ Rb,
    const float* __restrict__ nL, const float* __restrict__ nR,
    float* __restrict__ out)
{
    __shared__ unsigned short Als[BM * D_DIM];
    __shared__ unsigned short Bls[BN * D_DIM];
    __shared__ float nAs[BM];
    __shared__ float nBs[BN];

    const int tid  = threadIdx.x;
    const int bx   = blockIdx.x;   // M tile (cols)
    const int by   = blockIdx.y;   // N tile (rows)
    const int bz   = blockIdx.z;   // batch
    const int wid  = tid >> 6;
    const int lane = tid & 63;

    const bf16_t* aBase = Lb + ((size_t)bz * N_DIM + (size_t)by * BM) * D_DIM;
    const bf16_t* bBase = Rb + ((size_t)bz * M_DIM + (size_t)bx * BN) * D_DIM;

    char* AlsB = (char*)Als;
    char* BlsB = (char*)Bls;

    // ---- Stage A and B tiles (32 KB each) via direct-to-LDS DMA.
    // LDS granule g (16B) holds source granule (r = g>>4, c = (g&15) ^ (r&7)).
    #pragma unroll
    for (int i = 0; i < 8; ++i) {
        int g = (wid * 8 + i) * 64 + lane;    // [0, 2048)
        int r = g >> 4;
        int c = (g & 15) ^ (r & 7);
        GLOAD_LDS16(aBase + (size_t)r * D_DIM + c * 8, AlsB + (wid * 8 + i) * 1024);
    }
    #pragma unroll
    for (int i = 0; i < 8; ++i) {
        int g = (wid * 8 + i) * 64 + lane;
        int r = g >> 4;
        int c = (g & 15) ^ (r & 7);
        GLOAD_LDS16(bBase + (size_t)r * D_DIM + c * 8, BlsB + (wid * 8 + i) * 1024);
    }
    if (tid < 128) nAs[tid] = nL[bz * N_DIM + by * BM + tid];
    else           nBs[tid - 128] = nR[bz * M_DIM + bx * BN + (tid - 128)];
    __syncthreads();

    // ---- MFMA main: 4 waves, each owns 64x64 of the 128x128 tile
    const int wM = (wid >> 1) * 64;
    const int wN = (wid & 1) * 64;
    const int lr = lane & 15;          // fragment row (A) / col (B)

    f32x4 acc[4][4] = {};

    #pragma unroll
    for (int kk = 0; kk < 4; ++kk) {
        bf16x8 af[4], bfr[4];
        #pragma unroll
        for (int t = 0; t < 4; ++t) {
            int arow = wM + t * 16 + lr;
            int aoff = arow * 256 + kk * 64 + (lane >> 4) * 16;
            aoff ^= (arow & 7) << 4;
            af[t] = *(const bf16x8*)(AlsB + aoff);
            int brow = wN + t * 16 + lr;
            int boff = brow * 256 + kk * 64 + (lane >> 4) * 16;
            boff ^= (brow & 7) << 4;
            bfr[t] = *(const bf16x8*)(BlsB + boff);
        }
        #pragma unroll
        for (int mt = 0; mt < 4; ++mt)
            #pragma unroll
            for (int nt = 0; nt < 4; ++nt)
                acc[mt][nt] = __builtin_amdgcn_mfma_f32_16x16x32_bf16(
                    af[mt], bfr[nt], acc[mt][nt], 0, 0, 0);
    }

    // ---- Epilogue: d2 = l2 + r2 - 2*dot; out = 1/(1+sqrt(max(d2,0)))
    // C/D layout (16x16x32): col = lane&15, row = (lane>>4)*4 + reg
    const size_t outBase = ((size_t)bz * N_DIM + (size_t)by * BM) * M_DIM + (size_t)bx * BN;
    #pragma unroll
    for (int mt = 0; mt < 4; ++mt) {
        int rowb = wM + mt * 16 + (lane >> 4) * 4;
        #pragma unroll
        for (int nt = 0; nt < 4; ++nt) {
            int col_l = wN + nt * 16 + lr;
            float r2 = nBs[col_l];
            #pragma unroll
            for (int r = 0; r < 4; ++r) {
                int row_l = rowb + r;
                float l2 = nAs[row_l];
                float d2 = fmaf(-2.0f, acc[mt][nt][r], l2 + r2);
                d2 = fmaxf(d2, 0.0f);
                float o = 1.0f / (1.0f + sqrtf(d2));
                out[outBase + (size_t)row_l * M_DIM + col_l] = o;
            }
        }
    }
}

// ---------------------------------------------------------------------------
// Fallback (R0 kernel, known-passing) in case ws_size is too small.
// ---------------------------------------------------------------------------
__device__ inline unsigned short f32_to_bf16_rne(float f) {
    unsigned u = __float_as_uint(f);
    u += 0x7FFFu + ((u >> 16) & 1u);
    return (unsigned short)(u >> 16);
}

__global__ __launch_bounds__(256) void attn_dist_fallback(
    const float* __restrict__ L, const float* __restrict__ R,
    float* __restrict__ out)
{
    __shared__ unsigned short Als[BM * D_DIM];
    __shared__ unsigned short Bls[BN * D_DIM];
    __shared__ float normA[BM];
    __shared__ float normB[BN];

    const int tid = threadIdx.x;
    const int bx = blockIdx.x, by = blockIdx.y, bz = blockIdx.z;

    const float* aSrc = L + ((size_t)bz * N_DIM + (size_t)by * BM) * D_DIM;
    const float* bSrc = R + ((size_t)bz * M_DIM + (size_t)bx * BN) * D_DIM;

    char* AlsB = (char*)Als;
    char* BlsB = (char*)Bls;

    #pragma unroll
    for (int i = 0; i < 16; ++i) {
        int idx = tid + i * 256;
        int row = idx >> 5;
        int c4  = idx & 31;
        float4 va = ((const float4*)aSrc)[idx];
        float4 vb = ((const float4*)bSrc)[idx];
        ushort4 pa, pb;
        pa.x = f32_to_bf16_rne(va.x); pa.y = f32_to_bf16_rne(va.y);
        pa.z = f32_to_bf16_rne(va.z); pa.w = f32_to_bf16_rne(va.w);
        pb.x = f32_to_bf16_rne(vb.x); pb.y = f32_to_bf16_rne(vb.y);
        pb.z = f32_to_bf16_rne(vb.z); pb.w = f32_to_bf16_rne(vb.w);
        int off = row * 256 + c4 * 8;
        off ^= (row & 7) << 4;
        *(ushort4*)(AlsB + off) = pa;
        *(ushort4*)(BlsB + off) = pb;
    }
    __syncthreads();

    {
        int row = tid & 127;
        const char* base = (tid < 128) ? AlsB : BlsB;
        float s = 0.0f;
        #pragma unroll
        for (int c = 0; c < 16; ++c) {
            int off = row * 256 + c * 16;
            off ^= (row & 7) << 4;
            bf16x8 v = *(const bf16x8*)(base + off);
            #pragma unroll
            for (int j = 0; j < 8; ++j) {
                float x = (float)v[j];
                s = fmaf(x, x, s);
            }
        }
        if (tid < 128) normA[row] = s;
        else           normB[row] = s;
    }
    __syncthreads();

    const int wid  = tid >> 6;
    const int lane = tid & 63;
    const int wM = (wid >> 1) * 64;
    const int wN = (wid & 1) * 64;
    const int lr = lane & 15;
    const int lk = (lane >> 4) * 8;

    f32x4 acc[4][4] = {};

    #pragma unroll
    for (int kk = 0; kk < 4; ++kk) {
        bf16x8 af[4], bfr[4];
        #pragma unroll
        for (int t = 0; t < 4; ++t) {
            int arow = wM + t * 16 + lr;
            int aoff = arow * 256 + (kk * 32 + lk) * 2;
            aoff ^= (arow & 7) << 4;
            af[t] = *(const bf16x8*)(AlsB + aoff);
            int brow = wN + t * 16 + lr;
            int boff = brow * 256 + (kk * 32 + lk) * 2;
            boff ^= (brow & 7) << 4;
            bfr[t] = *(const bf16x8*)(BlsB + boff);
        }
        #pragma unroll
        for (int mt = 0; mt < 4; ++mt)
            #pragma unroll
            for (int nt = 0; nt < 4; ++nt)
                acc[mt][nt] = __builtin_amdgcn_mfma_f32_16x16x32_bf16(
                    af[mt], bfr[nt], acc[mt][nt], 0, 0, 0);
    }

    const size_t outBase = ((size_t)bz * N_DIM + (size_t)by * BM) * M_DIM + (size_t)bx * BN;
    #pragma unroll
    for (int mt = 0; mt < 4; ++mt) {
        int rowb = wM + mt * 16 + (lane >> 4) * 4;
        #pragma unroll
        for (int nt = 0; nt < 4; ++nt) {
            int col_l = wN + nt * 16 + lr;
            float r2 = normB[col_l];
            #pragma unroll
            for (int r = 0; r < 4; ++r) {
                int row_l = rowb + r;
                float l2 = normA[row_l];
                float d2 = fmaf(-2.0f, acc[mt][nt][r], l2 + r2);
                d2 = fmaxf(d2, 0.0f);
                float o = 1.0f / (1.0f + sqrtf(d2));
                out[outBase + (size_t)row_l * M_DIM + col_l] = o;
            }
        }
    }
}

extern "C" void kernel_launch(void* const* d_in, const int* in_sizes, int n_in,
                              void* d_out, int out_size, void* d_ws, size_t ws_size,
                              hipStream_t stream) {
    const float* L = (const float*)d_in[0];
    const float* R = (const float*)d_in[1];
    float* out = (float*)d_out;

    const size_t LB_BYTES = (size_t)B_DIM * N_DIM * D_DIM * 2;  // 4 MiB
    const size_t NL_BYTES = (size_t)B_DIM * N_DIM * 4;          // 64 KiB
    const size_t need = 2 * LB_BYTES + 2 * NL_BYTES;

    if (ws_size >= need) {
        char* ws = (char*)d_ws;
        bf16_t* Lb = (bf16_t*)ws;
        bf16_t* Rb = (bf16_t*)(ws + LB_BYTES);
        float*  nLp = (float*)(ws + 2 * LB_BYTES);
        float*  nRp = (float*)(ws + 2 * LB_BYTES + NL_BYTES);

        prep_kernel<<<dim3(2048, 2, 1), dim3(256), 0, stream>>>(L, R, Lb, Rb, nLp, nRp);
        dist_mfma_kernel<<<dim3(M_DIM / BN, N_DIM / BM, B_DIM), dim3(256), 0, stream>>>(
            Lb, Rb, nLp, nRp, out);
    } else {
        attn_dist_fallback<<<dim3(M_DIM / BN, N_DIM / BM, B_DIM), dim3(256), 0, stream>>>(L, R, out);
    }
}

// Round 3
// 46.512 us; speedup vs baseline: 1.2297x; 1.2297x over previous
//
#include <hip/hip_runtime.h>

// Problem constants (from reference setup_inputs): B=8, N=2048, M=2048, D=128
#define B_DIM 8
#define N_DIM 2048
#define M_DIM 2048
#define D_DIM 128
#define BM 128
#define BN 128

typedef __bf16 bf16_t;
typedef bf16_t bf16x4 __attribute__((ext_vector_type(4)));
typedef bf16_t bf16x8 __attribute__((ext_vector_type(8)));
typedef float f32x4 __attribute__((ext_vector_type(4)));

#define GLOAD_LDS16(g, l)                                              \
    __builtin_amdgcn_global_load_lds(                                  \
        (const __attribute__((address_space(1))) void*)(g),            \
        (__attribute__((address_space(3))) void*)(l), 16, 0, 0)

// ---------------------------------------------------------------------------
// Kernel 1: fp32 -> bf16 (RNE) conversion + row norms from the SAME rounded
// values. One wave handles 2 rows (64 lanes = 2 x 32 float4 slots).
// ---------------------------------------------------------------------------
__global__ __launch_bounds__(256) void prep_kernel(
    const float* __restrict__ L, const float* __restrict__ R,
    bf16_t* __restrict__ Lb, bf16_t* __restrict__ Rb,
    float* __restrict__ nL, float* __restrict__ nR)
{
    const int tid  = threadIdx.x;
    const int wid  = tid >> 6;
    const int lane = tid & 63;
    const int row  = blockIdx.x * 8 + wid * 2 + (lane >> 5);  // [0, 16384)
    const int c4   = lane & 31;                                // float4 slot in row

    const float* src  = blockIdx.y ? R : L;
    bf16_t*      dst  = blockIdx.y ? Rb : Lb;
    float*       ndst = blockIdx.y ? nR : nL;

    float4 v = ((const float4*)src)[(size_t)row * 32 + c4];
    bf16x4 p = { (bf16_t)v.x, (bf16_t)v.y, (bf16_t)v.z, (bf16_t)v.w };
    ((bf16x4*)dst)[(size_t)row * 32 + c4] = p;

    float x0 = (float)p[0], x1 = (float)p[1], x2 = (float)p[2], x3 = (float)p[3];
    float s = fmaf(x0, x0, fmaf(x1, x1, fmaf(x2, x2, x3 * x3)));
    #pragma unroll
    for (int off = 1; off < 32; off <<= 1) s += __shfl_xor(s, off);
    if (c4 == 0) ndst[row] = s;
}

// ---------------------------------------------------------------------------
// Kernel 2: bf16 MFMA distance tile. LDS staged via global_load_lds width=16
// with pre-swizzled SOURCE addresses (LDS dest stays linear); reads apply the
// same XOR swizzle:  granule c' = c ^ (row & 7)  (16B granules, 16 per row).
// MFMA operands are SWAPPED (mfma(B,A)): out-row = lane&15,
// out-col = (lane>>4)*4 + reg  =>  each lane's 4 regs = 4 consecutive columns
// => float4 stores, no LDS transpose.
// ---------------------------------------------------------------------------
__global__ __launch_bounds__(256) void dist_mfma_kernel(
    const bf16_t* __restrict__ Lb, const bf16_t* __restrict__ Rb,
    const float* __restrict__ nL, const float* __restrict__ nR,
    float* __restrict__ out)
{
    __shared__ unsigned short Als[BM * D_DIM];
    __shared__ unsigned short Bls[BN * D_DIM];
    __shared__ float nAs[BM];
    __shared__ float nBs[BN];

    const int tid  = threadIdx.x;
    const int bx   = blockIdx.x;   // M tile (cols)
    const int by   = blockIdx.y;   // N tile (rows)
    const int bz   = blockIdx.z;   // batch
    const int wid  = tid >> 6;
    const int lane = tid & 63;

    const bf16_t* aBase = Lb + ((size_t)bz * N_DIM + (size_t)by * BM) * D_DIM;
    const bf16_t* bBase = Rb + ((size_t)bz * M_DIM + (size_t)bx * BN) * D_DIM;

    char* AlsB = (char*)Als;
    char* BlsB = (char*)Bls;

    // ---- Stage A and B tiles (32 KB each) via direct-to-LDS DMA.
    // LDS granule g (16B) holds source granule (r = g>>4, c = (g&15) ^ (r&7)).
    #pragma unroll
    for (int i = 0; i < 8; ++i) {
        int g = (wid * 8 + i) * 64 + lane;    // [0, 2048)
        int r = g >> 4;
        int c = (g & 15) ^ (r & 7);
        GLOAD_LDS16(aBase + (size_t)r * D_DIM + c * 8, AlsB + (wid * 8 + i) * 1024);
    }
    #pragma unroll
    for (int i = 0; i < 8; ++i) {
        int g = (wid * 8 + i) * 64 + lane;
        int r = g >> 4;
        int c = (g & 15) ^ (r & 7);
        GLOAD_LDS16(bBase + (size_t)r * D_DIM + c * 8, BlsB + (wid * 8 + i) * 1024);
    }
    if (tid < 128) nAs[tid] = nL[bz * N_DIM + by * BM + tid];
    else           nBs[tid - 128] = nR[bz * M_DIM + bx * BN + (tid - 128)];
    __syncthreads();

    // ---- MFMA main: 4 waves, each owns 64x64 of the 128x128 tile
    const int wM = (wid >> 1) * 64;
    const int wN = (wid & 1) * 64;
    const int lr = lane & 15;          // fragment row (A) / col (B)

    f32x4 acc[4][4] = {};

    #pragma unroll
    for (int kk = 0; kk < 4; ++kk) {
        bf16x8 af[4], bfr[4];
        #pragma unroll
        for (int t = 0; t < 4; ++t) {
            int arow = wM + t * 16 + lr;
            int aoff = arow * 256 + kk * 64 + (lane >> 4) * 16;
            aoff ^= (arow & 7) << 4;
            af[t] = *(const bf16x8*)(AlsB + aoff);
            int brow = wN + t * 16 + lr;
            int boff = brow * 256 + kk * 64 + (lane >> 4) * 16;
            boff ^= (brow & 7) << 4;
            bfr[t] = *(const bf16x8*)(BlsB + boff);
        }
        // SWAPPED operands: D[b_row][a_row] -> out-row = lane&15 (a_row),
        // out-col = (lane>>4)*4 + reg (b_row).
        #pragma unroll
        for (int mt = 0; mt < 4; ++mt)
            #pragma unroll
            for (int nt = 0; nt < 4; ++nt)
                acc[mt][nt] = __builtin_amdgcn_mfma_f32_16x16x32_bf16(
                    bfr[nt], af[mt], acc[mt][nt], 0, 0, 0);
    }

    // ---- Epilogue: d2 = l2 + r2 - 2*dot; out = 1/(1+sqrt(max(d2,0)))
    // Each lane: row = wM + mt*16 + lr; cols = wN + nt*16 + (lane>>4)*4 + r
    const size_t outBase = ((size_t)bz * N_DIM + (size_t)by * BM) * M_DIM + (size_t)bx * BN;
    #pragma unroll
    for (int mt = 0; mt < 4; ++mt) {
        const int row_l = wM + mt * 16 + lr;
        const float l2 = nAs[row_l];
        float* orow = out + outBase + (size_t)row_l * M_DIM;
        #pragma unroll
        for (int nt = 0; nt < 4; ++nt) {
            const int colb = wN + nt * 16 + (lane >> 4) * 4;
            f32x4 r2v = *(const f32x4*)&nBs[colb];
            f32x4 a = acc[mt][nt];
            f32x4 o;
            #pragma unroll
            for (int r = 0; r < 4; ++r) {
                float d2 = fmaf(-2.0f, a[r], l2 + r2v[r]);
                d2 = fmaxf(d2, 0.0f);
                float s = __builtin_amdgcn_sqrtf(d2);
                o[r] = __builtin_amdgcn_rcpf(1.0f + s);
            }
            *(f32x4*)(orow + colb) = o;
        }
    }
}

// ---------------------------------------------------------------------------
// Fallback (R0 kernel, known-passing) in case ws_size is too small.
// ---------------------------------------------------------------------------
__device__ inline unsigned short f32_to_bf16_rne(float f) {
    unsigned u = __float_as_uint(f);
    u += 0x7FFFu + ((u >> 16) & 1u);
    return (unsigned short)(u >> 16);
}

__global__ __launch_bounds__(256) void attn_dist_fallback(
    const float* __restrict__ L, const float* __restrict__ R,
    float* __restrict__ out)
{
    __shared__ unsigned short Als[BM * D_DIM];
    __shared__ unsigned short Bls[BN * D_DIM];
    __shared__ float normA[BM];
    __shared__ float normB[BN];

    const int tid = threadIdx.x;
    const int bx = blockIdx.x, by = blockIdx.y, bz = blockIdx.z;

    const float* aSrc = L + ((size_t)bz * N_DIM + (size_t)by * BM) * D_DIM;
    const float* bSrc = R + ((size_t)bz * M_DIM + (size_t)bx * BN) * D_DIM;

    char* AlsB = (char*)Als;
    char* BlsB = (char*)Bls;

    #pragma unroll
    for (int i = 0; i < 16; ++i) {
        int idx = tid + i * 256;
        int row = idx >> 5;
        int c4  = idx & 31;
        float4 va = ((const float4*)aSrc)[idx];
        float4 vb = ((const float4*)bSrc)[idx];
        ushort4 pa, pb;
        pa.x = f32_to_bf16_rne(va.x); pa.y = f32_to_bf16_rne(va.y);
        pa.z = f32_to_bf16_rne(va.z); pa.w = f32_to_bf16_rne(va.w);
        pb.x = f32_to_bf16_rne(vb.x); pb.y = f32_to_bf16_rne(vb.y);
        pb.z = f32_to_bf16_rne(vb.z); pb.w = f32_to_bf16_rne(vb.w);
        int off = row * 256 + c4 * 8;
        off ^= (row & 7) << 4;
        *(ushort4*)(AlsB + off) = pa;
        *(ushort4*)(BlsB + off) = pb;
    }
    __syncthreads();

    {
        int row = tid & 127;
        const char* base = (tid < 128) ? AlsB : BlsB;
        float s = 0.0f;
        #pragma unroll
        for (int c = 0; c < 16; ++c) {
            int off = row * 256 + c * 16;
            off ^= (row & 7) << 4;
            bf16x8 v = *(const bf16x8*)(base + off);
            #pragma unroll
            for (int j = 0; j < 8; ++j) {
                float x = (float)v[j];
                s = fmaf(x, x, s);
            }
        }
        if (tid < 128) normA[row] = s;
        else           normB[row] = s;
    }
    __syncthreads();

    const int wid  = tid >> 6;
    const int lane = tid & 63;
    const int wM = (wid >> 1) * 64;
    const int wN = (wid & 1) * 64;
    const int lr = lane & 15;

    f32x4 acc[4][4] = {};

    #pragma unroll
    for (int kk = 0; kk < 4; ++kk) {
        bf16x8 af[4], bfr[4];
        #pragma unroll
        for (int t = 0; t < 4; ++t) {
            int arow = wM + t * 16 + lr;
            int aoff = arow * 256 + (kk * 32 + (lane >> 4) * 8) * 2;
            aoff ^= (arow & 7) << 4;
            af[t] = *(const bf16x8*)(AlsB + aoff);
            int brow = wN + t * 16 + lr;
            int boff = brow * 256 + (kk * 32 + (lane >> 4) * 8) * 2;
            boff ^= (brow & 7) << 4;
            bfr[t] = *(const bf16x8*)(BlsB + boff);
        }
        #pragma unroll
        for (int mt = 0; mt < 4; ++mt)
            #pragma unroll
            for (int nt = 0; nt < 4; ++nt)
                acc[mt][nt] = __builtin_amdgcn_mfma_f32_16x16x32_bf16(
                    bfr[nt], af[mt], acc[mt][nt], 0, 0, 0);
    }

    const size_t outBase = ((size_t)bz * N_DIM + (size_t)by * BM) * M_DIM + (size_t)bx * BN;
    #pragma unroll
    for (int mt = 0; mt < 4; ++mt) {
        const int row_l = wM + mt * 16 + lr;
        const float l2 = normA[row_l];
        float* orow = out + outBase + (size_t)row_l * M_DIM;
        #pragma unroll
        for (int nt = 0; nt < 4; ++nt) {
            const int colb = wN + nt * 16 + (lane >> 4) * 4;
            f32x4 r2v = *(const f32x4*)&normB[colb];
            f32x4 a = acc[mt][nt];
            f32x4 o;
            #pragma unroll
            for (int r = 0; r < 4; ++r) {
                float d2 = fmaf(-2.0f, a[r], l2 + r2v[r]);
                d2 = fmaxf(d2, 0.0f);
                float s = __builtin_amdgcn_sqrtf(d2);
                o[r] = __builtin_amdgcn_rcpf(1.0f + s);
            }
            *(f32x4*)(orow + colb) = o;
        }
    }
}

extern "C" void kernel_launch(void* const* d_in, const int* in_sizes, int n_in,
                              void* d_out, int out_size, void* d_ws, size_t ws_size,
                              hipStream_t stream) {
    const float* L = (const float*)d_in[0];
    const float* R = (const float*)d_in[1];
    float* out = (float*)d_out;

    const size_t LB_BYTES = (size_t)B_DIM * N_DIM * D_DIM * 2;  // 4 MiB
    const size_t NL_BYTES = (size_t)B_DIM * N_DIM * 4;          // 64 KiB
    const size_t need = 2 * LB_BYTES + 2 * NL_BYTES;

    if (ws_size >= need) {
        char* ws = (char*)d_ws;
        bf16_t* Lb = (bf16_t*)ws;
        bf16_t* Rb = (bf16_t*)(ws + LB_BYTES);
        float*  nLp = (float*)(ws + 2 * LB_BYTES);
        float*  nRp = (float*)(ws + 2 * LB_BYTES + NL_BYTES);

        prep_kernel<<<dim3(2048, 2, 1), dim3(256), 0, stream>>>(L, R, Lb, Rb, nLp, nRp);
        dist_mfma_kernel<<<dim3(M_DIM / BN, N_DIM / BM, B_DIM), dim3(256), 0, stream>>>(
            Lb, Rb, nLp, nRp, out);
    } else {
        attn_dist_fallback<<<dim3(M_DIM / BN, N_DIM / BM, B_DIM), dim3(256), 0, stream>>>(L, R, out);
    }
}